// Round 4
// baseline (598.091 us; speedup 1.0000x reference)
//
#include <hip/hip_runtime.h>

typedef __bf16 bf16_t;
typedef __attribute__((ext_vector_type(4))) __bf16 bf16x4;
typedef __attribute__((ext_vector_type(8))) __bf16 bf16x8;
typedef __attribute__((ext_vector_type(4))) float f32x4;

#define MFMA_BF16(a, b, c) __builtin_amdgcn_mfma_f32_16x16x32_bf16((a), (b), (c), 0, 0, 0)

namespace {

constexpr int PIMG  = 5;
constexpr int TTOK  = 576;
constexpr int CCH   = 1280;
constexpr int NSEL  = 288;
constexpr int NH    = 20;
constexpr int ROWS  = 2 * PIMG * TTOK;     // 5760
constexpr int TKEYS = 4 * NSEL + TTOK;     // 1728
constexpr int KT_TILES = TKEYS / 64;       // 27 (divisible by 3 for the unroll)
constexpr size_t NXE = (size_t)ROWS * CCH;   // 7372800
constexpr size_t NWE = (size_t)CCH * CCH;    // 1638400

__device__ __forceinline__ bf16x8 cvt8(const float* p) {
  const float4 f0 = *(const float4*)p;
  const float4 f1 = *(const float4*)(p + 4);
  bf16x8 r;
  r[0] = (bf16_t)f0.x; r[1] = (bf16_t)f0.y; r[2] = (bf16_t)f0.z; r[3] = (bf16_t)f0.w;
  r[4] = (bf16_t)f1.x; r[5] = (bf16_t)f1.y; r[6] = (bf16_t)f1.z; r[7] = (bf16_t)f1.w;
  return r;
}

// ---- one-shot f32 -> bf16 conversion of X and the 4 weight matrices ----
__global__ __launch_bounds__(256) void cvt_kernel(
    const float* __restrict__ X, const float* __restrict__ W0, const float* __restrict__ W1,
    const float* __restrict__ W2, const float* __restrict__ W3,
    bf16_t* __restrict__ Xb, bf16_t* __restrict__ Wb0, bf16_t* __restrict__ Wb1,
    bf16_t* __restrict__ Wb2, bf16_t* __restrict__ Wb3) {
  const int y = blockIdx.y;
  const float* src = y == 0 ? X : (y == 1 ? W0 : (y == 2 ? W1 : (y == 3 ? W2 : W3)));
  bf16_t* dst = y == 0 ? Xb : (y == 1 ? Wb0 : (y == 2 ? Wb1 : (y == 3 ? Wb2 : Wb3)));
  const size_t n = y == 0 ? NXE : NWE;
  const size_t idx = ((size_t)blockIdx.x * 256 + threadIdx.x) * 8;
  if (idx < n) *(bf16x8*)&dst[idx] = cvt8(&src[idx]);
}

// NT GEMM: C[m][n] = sum_k A[m][k]*B[n][k] (+bias) (*scale), bf16 in, fp32 acc.
// 128x128 tile, BK=64, register-prefetch pipeline (measured best of 3 variants).
template <bool BIAS, typename CT>
__device__ __forceinline__ void gemm_nt_body(const bf16_t* __restrict__ A,
                                             const bf16_t* __restrict__ B,
                                             const float* __restrict__ bias,
                                             CT* __restrict__ C,
                                             int bm, int bn, float scale) {
  constexpr int LDT = 72;  // 64 + 8 pad
  __shared__ bf16_t As[128 * LDT];
  __shared__ bf16_t Bs[128 * LDT];

  const int tid  = threadIdx.x;
  const int lane = tid & 63;
  const int wave = tid >> 6;
  const int quad = lane >> 4;
  const int l16  = lane & 15;
  const int wr   = (wave >> 1) * 64;
  const int wc   = (wave & 1) * 64;
  const int m0   = bm * 128;
  const int n0   = bn * 128;
  const int srow = tid >> 3;        // 0..31 (+32p)
  const int scol = (tid & 7) * 8;   // 0..56

  bf16x8 pa[4], pb[4];
  auto loadAB = [&](int k0) {
#pragma unroll
    for (int p = 0; p < 4; ++p) {
      pa[p] = *(const bf16x8*)&A[(size_t)(m0 + srow + 32 * p) * CCH + k0 + scol];
      pb[p] = *(const bf16x8*)&B[(size_t)(n0 + srow + 32 * p) * CCH + k0 + scol];
    }
  };
  loadAB(0);

  f32x4 acc[4][4];
#pragma unroll
  for (int i = 0; i < 4; ++i)
#pragma unroll
    for (int j = 0; j < 4; ++j) acc[i][j] = (f32x4){0.f, 0.f, 0.f, 0.f};

  for (int it = 0; it < CCH / 64; ++it) {
#pragma unroll
    for (int p = 0; p < 4; ++p) {
      *(bf16x8*)&As[(srow + 32 * p) * LDT + scol] = pa[p];
      *(bf16x8*)&Bs[(srow + 32 * p) * LDT + scol] = pb[p];
    }
    __syncthreads();
    if (it < CCH / 64 - 1) loadAB((it + 1) * 64);  // in flight during compute
#pragma unroll
    for (int ks = 0; ks < 2; ++ks) {
      bf16x8 af[4], bfr[4];
#pragma unroll
      for (int i = 0; i < 4; ++i)
        af[i] = *(const bf16x8*)&As[(wr + 16 * i + l16) * LDT + ks * 32 + quad * 8];
#pragma unroll
      for (int j = 0; j < 4; ++j)
        bfr[j] = *(const bf16x8*)&Bs[(wc + 16 * j + l16) * LDT + ks * 32 + quad * 8];
#pragma unroll
      for (int i = 0; i < 4; ++i)
#pragma unroll
        for (int j = 0; j < 4; ++j)
          acc[i][j] = MFMA_BF16(af[i], bfr[j], acc[i][j]);
    }
    if (it < CCH / 64 - 1) __syncthreads();
  }

  // epilogue: C/D layout col = l16, row = quad*4 + r
#pragma unroll
  for (int j = 0; j < 4; ++j) {
    const int col = n0 + wc + 16 * j + l16;
    const float bv = BIAS ? bias[col] : 0.f;
#pragma unroll
    for (int i = 0; i < 4; ++i) {
#pragma unroll
      for (int r = 0; r < 4; ++r) {
        const int row = m0 + wr + 16 * i + quad * 4 + r;
        const float val = acc[i][j][r] * scale + bv;
        if constexpr (sizeof(CT) == 2)
          C[(size_t)row * CCH + col] = (CT)val;
        else
          C[(size_t)row * CCH + col] = val;
      }
    }
  }
}

__global__ __launch_bounds__(256, 3) void qkv_gemm_kernel(
    const bf16_t* __restrict__ Xb,
    const bf16_t* __restrict__ Wqb, const bf16_t* __restrict__ Wkb, const bf16_t* __restrict__ Wvb,
    bf16_t* __restrict__ Qf, bf16_t* __restrict__ Kf, bf16_t* __restrict__ Vf) {
  const bf16_t* W = blockIdx.z == 0 ? Wqb : (blockIdx.z == 1 ? Wkb : Wvb);
  bf16_t* O = blockIdx.z == 0 ? Qf : (blockIdx.z == 1 ? Kf : Vf);
  const float scl = blockIdx.z == 0 ? 0.125f : 1.0f;  // fold 1/sqrt(64) into Q
  gemm_nt_body<false, bf16_t>(Xb, W, nullptr, O, blockIdx.x, blockIdx.y, scl);
}

__global__ __launch_bounds__(256, 3) void out_gemm_kernel(
    const bf16_t* __restrict__ Of, const bf16_t* __restrict__ Wob,
    const float* __restrict__ bo, float* __restrict__ out) {
  gemm_nt_body<true, float>(Of, Wob, bo, out, blockIdx.x, blockIdx.y, 1.0f);
}

// Flash attention over gathered K/V rows. grid = 1800 linear, XCD-swizzled so the
// 9 qt-siblings of each (si,h) group (identical K/V reads) land on ONE XCD ->
// L2 reuse. block = 256 (4 waves). QB=64 (R2's QB=144 regressed: latency-bound,
// occupancy matters more than request count).
//
// R3/R4: barrier-drain convoy theory. __syncthreads() compiles to
// s_waitcnt vmcnt(0)+s_barrier, so the gather prefetch issued each iteration
// was force-completed ~400 cy later at the mid-iteration barrier -> every
// iteration convoys on full scattered-gather latency (explains R0/R1 null,
// R2 regression; per-block iter wall ~4300 cy vs ~600 cy visible work).
// Fix: raw s_barrier + manual lgkmcnt(0) (LDS visibility only; vmcnt stays
// counted -> loads live across barriers) + 2-deep tile prefetch with rotating
// NAMED register sets via x3-unrolled loop (no reg copies: a cur=next mov
// would force an early vmcnt wait and re-serialize).
// (R3 bench was lost to a container-acquisition failure; resubmitted unchanged.)
__global__ __launch_bounds__(256, 4) void attn_kernel(
    const bf16_t* __restrict__ Qf, const bf16_t* __restrict__ Kf, const bf16_t* __restrict__ Vf,
    const int* __restrict__ indices, bf16_t* __restrict__ Ofull) {
  __shared__ unsigned short kvrow[TKEYS];  // gathered key -> global row (<5760)
  __shared__ bf16_t Vts[2][64 * 64];    // dbuf V^T swizzled: V[key][dim] at [dim*64 + (key ^ (dim&56))]
  __shared__ bf16_t Ps[2][64 * 72];     // dbuf P[q][key], stride 72

  const int tid  = threadIdx.x;
  const int lane = tid & 63;
  const int wave = tid >> 6;
  const int quad = lane >> 4;
  const int l16  = lane & 15;

  // XCD swizzle: b%8 = XCD (round-robin dispatch heuristic; speed-only)
  const int b   = blockIdx.x;
  const int xcd = b & 7;
  const int t   = b >> 3;            // 0..224
  const int gi  = t / 9;
  const int qt  = t - gi * 9;        // sibling index = q-tile
  const int g   = xcd + 8 * gi;      // 0..199 group id
  const int h   = g % NH;
  const int si  = g / NH;            // s*5 + i
  const int s   = si / PIMG;
  const int ii  = si % PIMG;

  const int r0 = si * TTOK + qt * 64;
  const int hc = h * 64;

  // Q B-frags in registers, loop-invariant: aq[n][h2] -> B[q=16n+l16][k=quad*8+j+32*h2]
  bf16x8 aq[4][2];
#pragma unroll
  for (int n = 0; n < 4; ++n)
#pragma unroll
    for (int h2 = 0; h2 < 2; ++h2)
      aq[n][h2] = *(const bf16x8*)&Qf[(size_t)(r0 + 16 * n + l16) * CCH + hc + quad * 8 + 32 * h2];

  // key order: for p != ii ascending: gathered[p][0..287]; then own tokens 0..575
  for (int j = tid; j < TKEYS; j += 256) {
    int row;
    if (j < 4 * NSEL) {
      const int jp = j / NSEL;
      const int jj = j - jp * NSEL;
      const int p  = jp + (jp >= ii ? 1 : 0);
      row = (s * PIMG + p) * TTOK + indices[p * NSEL + jj];
    } else {
      row = si * TTOK + (j - 4 * NSEL);
    }
    kvrow[j] = (unsigned short)row;
  }
  __syncthreads();  // kvrow ready (full drain fine: one-time)

  const int jrow = tid >> 3;        // key 0..31 (and +32) for V staging
  const int cdim = (tid & 7) * 8;   // dim chunk for V staging
  const int cb0 = jrow ^ cdim;      // key ^ (dim&56): cdim == dim&56 for all x
  const int cb1 = (jrow + 32) ^ cdim;

  // tile register sets: T[0]=K lo, T[1]=K hi, T[2]=V row a, T[3]=V row b
  auto load_tile = [&](int kt, bf16x8 (&T)[4]) {
    const int krow = kvrow[kt * 64 + 16 * wave + l16];
    T[0] = *(const bf16x8*)&Kf[(size_t)krow * CCH + hc + quad * 8];
    T[1] = *(const bf16x8*)&Kf[(size_t)krow * CCH + hc + quad * 8 + 32];
    const int ra = kvrow[kt * 64 + jrow];
    const int rb = kvrow[kt * 64 + jrow + 32];
    T[2] = *(const bf16x8*)&Vf[(size_t)ra * CCH + hc + cdim];
    T[3] = *(const bf16x8*)&Vf[(size_t)rb * CCH + hc + cdim];
  };

  bf16x8 TA[4], TB[4], TC[4];
  load_tile(0, TA);
  load_tile(1, TB);

  float l_part[4] = {0.f, 0.f, 0.f, 0.f};
  f32x4 oacc[4];
#pragma unroll
  for (int n = 0; n < 4; ++n) oacc[n] = (f32x4){0.f, 0.f, 0.f, 0.f};

  // one iteration; CUR = tile kt's regs, FUT gets tile kt+2's loads
  auto body = [&](int kt, bf16x8 (&CUR)[4], bf16x8 (&FUT)[4]) {
    // issue prefetch kt+2 FIRST: ~2 iterations of slack before consumption
    if (kt + 2 < KT_TILES) load_tile(kt + 2, FUT);

    bf16_t* __restrict__ Vcur = &Vts[kt & 1][0];
    bf16_t* __restrict__ Pcur = &Ps[kt & 1][0];

    // ---- commit staged V tile (transposed, swizzled) into buf[kt&1] ----
    // safe WAR: prior reads of this buffer (PV at kt-2) were lgkm-drained
    // before barrier(kt-1), which every wave passed before reaching here.
#pragma unroll
    for (int x = 0; x < 8; ++x) {
      Vcur[(cdim + x) * 64 + cb0] = CUR[2][x];
      Vcur[(cdim + x) * 64 + cb1] = CUR[3][x];
    }

    // ---- S^T = K Q^T for wave's 16 keys x all 64 q (K frags from registers) ----
    f32x4 sacc[4];
#pragma unroll
    for (int n = 0; n < 4; ++n) {
      f32x4 z = (f32x4){0.f, 0.f, 0.f, 0.f};
      z = MFMA_BF16(CUR[0], aq[n][0], z);
      z = MFMA_BF16(CUR[1], aq[n][1], z);
      sacc[n] = z;
    }

    // ---- softmax (m=0): lane holds keys 16w+4*quad+r for q=16n+l16 ----
#pragma unroll
    for (int n = 0; n < 4; ++n) {
      bf16x4 pb;
      float sum = 0.f;
#pragma unroll
      for (int r = 0; r < 4; ++r) {
        const float pv = __expf(sacc[n][r]);
        pb[r] = (bf16_t)pv;
        sum += pv;
      }
      l_part[n] += sum;
      *(bf16x4*)&Pcur[(16 * n + l16) * 72 + 16 * wave + 4 * quad] = pb;
    }

    // ---- THE barrier: LDS visibility only; vmcnt NOT drained so the
    // kt+1/kt+2 gather loads stay in flight across it (T4) ----
    asm volatile("s_waitcnt lgkmcnt(0)" ::: "memory");
    __builtin_amdgcn_s_barrier();
    asm volatile("" ::: "memory");

    // ---- O[q][16w..16w+15] += P V : A=P frags, B=V^T frags (dims of wave w) ----
    const bf16x8 vf0 = *(const bf16x8*)&Vcur[(16 * wave + l16) * 64 + ((quad * 8) ^ ((16 * wave + l16) & 56))];
    const bf16x8 vf1 = *(const bf16x8*)&Vcur[(16 * wave + l16) * 64 + ((quad * 8 + 32) ^ ((16 * wave + l16) & 56))];
#pragma unroll
    for (int n = 0; n < 4; ++n) {
      const bf16x8 pf0 = *(const bf16x8*)&Pcur[(16 * n + l16) * 72 + quad * 8];
      const bf16x8 pf1 = *(const bf16x8*)&Pcur[(16 * n + l16) * 72 + quad * 8 + 32];
      oacc[n] = MFMA_BF16(pf0, vf0, oacc[n]);
      oacc[n] = MFMA_BF16(pf1, vf1, oacc[n]);
    }
    // no trailing barrier (dbuf): buf[kt&1] is next written at kt+2, after
    // barrier(kt+1); every wave's PV reads here are lgkm-drained before it
    // reaches barrier(kt+1), so the WAR hazard is closed chip-wide.
  };

  // x3-unrolled rotation: tile kt is consumed from the set loaded 2 calls ago.
  for (int base = 0; base < KT_TILES; base += 3) {
    body(base + 0, TA, TC);
    body(base + 1, TB, TA);
    body(base + 2, TC, TB);
  }

  __syncthreads();  // full drain before aliasing Ps/Vts as scratch

  // ---- merge l partials (alias dead Ps/Vts as reduction scratch) and write O ----
  float* lred = (float*)&Ps[0][0];    // 64*16 floats = 4 KB
  float* linv = (float*)&Vts[0][0];   // 64 floats
#pragma unroll
  for (int n = 0; n < 4; ++n)
    lred[(16 * n + l16) * 16 + 4 * wave + quad] = l_part[n];
  __syncthreads();
  if (tid < 64) {
    float tt = 0.f;
#pragma unroll
    for (int i = 0; i < 16; ++i) tt += lred[tid * 16 + i];
    linv[tid] = 1.f / tt;
  }
  __syncthreads();
#pragma unroll
  for (int n = 0; n < 4; ++n) {
#pragma unroll
    for (int r = 0; r < 4; ++r) {
      const int qloc = 16 * n + 4 * quad + r;
      Ofull[(size_t)(r0 + qloc) * CCH + hc + 16 * wave + l16] =
          (bf16_t)(oacc[n][r] * linv[qloc]);
    }
  }
}

}  // namespace

extern "C" void kernel_launch(void* const* d_in, const int* in_sizes, int n_in,
                              void* d_out, int out_size, void* d_ws, size_t ws_size,
                              hipStream_t stream) {
  const float* hs = (const float*)d_in[0];
  const float* Wq = (const float*)d_in[1];
  const float* Wk = (const float*)d_in[2];
  const float* Wv = (const float*)d_in[3];
  const float* Wo = (const float*)d_in[4];
  const float* bo = (const float*)d_in[5];
  const int* indices = (const int*)d_in[6];
  float* out = (float*)d_out;

  // ws layout (bf16): Qf, Kf, Vf, Xb(->Of after qkv gemm), Wqb, Wkb, Wvb, Wob = 72.1 MB
  bf16_t* Qf  = (bf16_t*)d_ws;
  bf16_t* Kf  = Qf + NXE;
  bf16_t* Vf  = Kf + NXE;
  bf16_t* Xb  = Vf + NXE;     // dead after qkv gemm
  bf16_t* Of  = Xb;           // attn output reuses the slot
  bf16_t* Wqb = Xb + NXE;
  bf16_t* Wkb = Wqb + NWE;
  bf16_t* Wvb = Wkb + NWE;
  bf16_t* Wob = Wvb + NWE;

  dim3 g0((NXE + 2047) / 2048, 5);
  cvt_kernel<<<g0, dim3(256), 0, stream>>>(hs, Wq, Wk, Wv, Wo, Xb, Wqb, Wkb, Wvb, Wob);

  dim3 g1(ROWS / 128, CCH / 128, 3);
  qkv_gemm_kernel<<<g1, dim3(256), 0, stream>>>(Xb, Wqb, Wkb, Wvb, Qf, Kf, Vf);

  attn_kernel<<<dim3(1800), dim3(256), 0, stream>>>(Qf, Kf, Vf, indices, Of);

  dim3 g3(ROWS / 128, CCH / 128, 1);
  out_gemm_kernel<<<g3, dim3(256), 0, stream>>>(Of, Wob, bo, out);
}

// Round 5
// 419.564 us; speedup vs baseline: 1.4255x; 1.4255x over previous
//
#include <hip/hip_runtime.h>

typedef __bf16 bf16_t;
typedef __attribute__((ext_vector_type(4))) __bf16 bf16x4;
typedef __attribute__((ext_vector_type(8))) __bf16 bf16x8;
typedef __attribute__((ext_vector_type(4))) float f32x4;

#define MFMA_BF16(a, b, c) __builtin_amdgcn_mfma_f32_16x16x32_bf16((a), (b), (c), 0, 0, 0)

namespace {

constexpr int PIMG  = 5;
constexpr int TTOK  = 576;
constexpr int CCH   = 1280;
constexpr int NSEL  = 288;
constexpr int NH    = 20;
constexpr int ROWS  = 2 * PIMG * TTOK;     // 5760
constexpr int TKEYS = 4 * NSEL + TTOK;     // 1728
constexpr int KT_TILES = TKEYS / 64;       // 27
constexpr size_t NXE = (size_t)ROWS * CCH;   // 7372800
constexpr size_t NWE = (size_t)CCH * CCH;    // 1638400

__device__ __forceinline__ bf16x8 cvt8(const float* p) {
  const float4 f0 = *(const float4*)p;
  const float4 f1 = *(const float4*)(p + 4);
  bf16x8 r;
  r[0] = (bf16_t)f0.x; r[1] = (bf16_t)f0.y; r[2] = (bf16_t)f0.z; r[3] = (bf16_t)f0.w;
  r[4] = (bf16_t)f1.x; r[5] = (bf16_t)f1.y; r[6] = (bf16_t)f1.z; r[7] = (bf16_t)f1.w;
  return r;
}

// ---- one-shot f32 -> bf16 conversion of X and the 4 weight matrices ----
__global__ __launch_bounds__(256) void cvt_kernel(
    const float* __restrict__ X, const float* __restrict__ W0, const float* __restrict__ W1,
    const float* __restrict__ W2, const float* __restrict__ W3,
    bf16_t* __restrict__ Xb, bf16_t* __restrict__ Wb0, bf16_t* __restrict__ Wb1,
    bf16_t* __restrict__ Wb2, bf16_t* __restrict__ Wb3) {
  const int y = blockIdx.y;
  const float* src = y == 0 ? X : (y == 1 ? W0 : (y == 2 ? W1 : (y == 3 ? W2 : W3)));
  bf16_t* dst = y == 0 ? Xb : (y == 1 ? Wb0 : (y == 2 ? Wb1 : (y == 3 ? Wb2 : Wb3)));
  const size_t n = y == 0 ? NXE : NWE;
  const size_t idx = ((size_t)blockIdx.x * 256 + threadIdx.x) * 8;
  if (idx < n) *(bf16x8*)&dst[idx] = cvt8(&src[idx]);
}

// NT GEMM: C[m][n] = sum_k A[m][k]*B[n][k] (+bias) (*scale), bf16 in, fp32 acc.
// 128x128 tile, BK=64, register-prefetch pipeline (measured best of 3 variants).
template <bool BIAS, typename CT>
__device__ __forceinline__ void gemm_nt_body(const bf16_t* __restrict__ A,
                                             const bf16_t* __restrict__ B,
                                             const float* __restrict__ bias,
                                             CT* __restrict__ C,
                                             int bm, int bn, float scale) {
  constexpr int LDT = 72;  // 64 + 8 pad
  __shared__ bf16_t As[128 * LDT];
  __shared__ bf16_t Bs[128 * LDT];

  const int tid  = threadIdx.x;
  const int lane = tid & 63;
  const int wave = tid >> 6;
  const int quad = lane >> 4;
  const int l16  = lane & 15;
  const int wr   = (wave >> 1) * 64;
  const int wc   = (wave & 1) * 64;
  const int m0   = bm * 128;
  const int n0   = bn * 128;
  const int srow = tid >> 3;        // 0..31 (+32p)
  const int scol = (tid & 7) * 8;   // 0..56

  bf16x8 pa[4], pb[4];
  auto loadAB = [&](int k0) {
#pragma unroll
    for (int p = 0; p < 4; ++p) {
      pa[p] = *(const bf16x8*)&A[(size_t)(m0 + srow + 32 * p) * CCH + k0 + scol];
      pb[p] = *(const bf16x8*)&B[(size_t)(n0 + srow + 32 * p) * CCH + k0 + scol];
    }
  };
  loadAB(0);

  f32x4 acc[4][4];
#pragma unroll
  for (int i = 0; i < 4; ++i)
#pragma unroll
    for (int j = 0; j < 4; ++j) acc[i][j] = (f32x4){0.f, 0.f, 0.f, 0.f};

  for (int it = 0; it < CCH / 64; ++it) {
#pragma unroll
    for (int p = 0; p < 4; ++p) {
      *(bf16x8*)&As[(srow + 32 * p) * LDT + scol] = pa[p];
      *(bf16x8*)&Bs[(srow + 32 * p) * LDT + scol] = pb[p];
    }
    __syncthreads();
    if (it < CCH / 64 - 1) loadAB((it + 1) * 64);  // in flight during compute
#pragma unroll
    for (int ks = 0; ks < 2; ++ks) {
      bf16x8 af[4], bfr[4];
#pragma unroll
      for (int i = 0; i < 4; ++i)
        af[i] = *(const bf16x8*)&As[(wr + 16 * i + l16) * LDT + ks * 32 + quad * 8];
#pragma unroll
      for (int j = 0; j < 4; ++j)
        bfr[j] = *(const bf16x8*)&Bs[(wc + 16 * j + l16) * LDT + ks * 32 + quad * 8];
#pragma unroll
      for (int i = 0; i < 4; ++i)
#pragma unroll
        for (int j = 0; j < 4; ++j)
          acc[i][j] = MFMA_BF16(af[i], bfr[j], acc[i][j]);
    }
    if (it < CCH / 64 - 1) __syncthreads();
  }

  // epilogue: C/D layout col = l16, row = quad*4 + r
#pragma unroll
  for (int j = 0; j < 4; ++j) {
    const int col = n0 + wc + 16 * j + l16;
    const float bv = BIAS ? bias[col] : 0.f;
#pragma unroll
    for (int i = 0; i < 4; ++i) {
#pragma unroll
      for (int r = 0; r < 4; ++r) {
        const int row = m0 + wr + 16 * i + quad * 4 + r;
        const float val = acc[i][j][r] * scale + bv;
        if constexpr (sizeof(CT) == 2)
          C[(size_t)row * CCH + col] = (CT)val;
        else
          C[(size_t)row * CCH + col] = val;
      }
    }
  }
}

__global__ __launch_bounds__(256, 3) void qkv_gemm_kernel(
    const bf16_t* __restrict__ Xb,
    const bf16_t* __restrict__ Wqb, const bf16_t* __restrict__ Wkb, const bf16_t* __restrict__ Wvb,
    bf16_t* __restrict__ Qf, bf16_t* __restrict__ Kf, bf16_t* __restrict__ Vf) {
  const bf16_t* W = blockIdx.z == 0 ? Wqb : (blockIdx.z == 1 ? Wkb : Wvb);
  bf16_t* O = blockIdx.z == 0 ? Qf : (blockIdx.z == 1 ? Kf : Vf);
  const float scl = blockIdx.z == 0 ? 0.125f : 1.0f;  // fold 1/sqrt(64) into Q
  gemm_nt_body<false, bf16_t>(Xb, W, nullptr, O, blockIdx.x, blockIdx.y, scl);
}

__global__ __launch_bounds__(256, 3) void out_gemm_kernel(
    const bf16_t* __restrict__ Of, const bf16_t* __restrict__ Wob,
    const float* __restrict__ bo, float* __restrict__ out) {
  gemm_nt_body<true, float>(Of, Wob, bo, out, blockIdx.x, blockIdx.y, 1.0f);
}

// Flash attention over gathered K/V rows. grid = 1800, XCD-swizzled (9 qt-siblings
// of each (si,h) group share one XCD's L2). block = 256 (4 waves), 64 q/block.
//
// R5 structure (LDS-pipe theory): R0-R2 showed all pipes <35% yet flat; tally
// showed the LDS pipe at 80-100% (P round-trip 12 KB/wave/iter + 16 scalar V
// writes) with the vf reads a 16-way bank conflict (298 cy/iter, matches
// SQ_LDS_BANK_CONFLICT). Changes:
//  1. Waves split by q (16 rows each, all 64 keys), not by key. K rows are
//     gathered in bit-permuted order sig(row): [kt2|a|quad|r]->[kt2|quad|a|r],
//     so each lane's softmax output IS its PV A-frag -> P never leaves
//     registers (removes 4 ds_write_b64 + 8 ds_read_b128 per wave per iter).
//     Cost: K gather x4 redundant across waves (same lines, L1-absorbed).
//  2. V commit stages key-pairs (2j,2j+1) packed into dwords: 8 ds_write_b32
//     instead of 16 ds_write_b16.
//  3. V^T swizzle col = key ^ ((d&56)^((d&7)<<3)): 2-way (free) on writes,
//     exactly 8 lanes per bank-group (zero conflict) on reads.
// Plain __syncthreads only (R4: asm memory clobbers caused 530 MB scratch
// spill traffic by blocking remat — never again in this loop).
__global__ __launch_bounds__(256, 4) void attn_kernel(
    const bf16_t* __restrict__ Qf, const bf16_t* __restrict__ Kf, const bf16_t* __restrict__ Vf,
    const int* __restrict__ indices, bf16_t* __restrict__ Ofull) {
  __shared__ unsigned short kvrow[TKEYS];  // gathered key -> global row (<5760)
  __shared__ bf16_t Vts[2][64 * 64];       // dbuf V^T: V[key][d] at [d*64 + (key ^ swz(d))]

  const int tid  = threadIdx.x;
  const int lane = tid & 63;
  const int wave = tid >> 6;
  const int quad = lane >> 4;
  const int l16  = lane & 15;

  // XCD swizzle: b%8 = XCD (round-robin dispatch heuristic; speed-only)
  const int b   = blockIdx.x;
  const int xcd = b & 7;
  const int t   = b >> 3;            // 0..224
  const int gi  = t / 9;
  const int qt  = t - gi * 9;        // sibling index = q-tile
  const int g   = xcd + 8 * gi;      // 0..199 group id
  const int h   = g % NH;
  const int si  = g / NH;            // s*5 + i
  const int s   = si / PIMG;
  const int ii  = si % PIMG;

  const int r0 = si * TTOK + qt * 64;
  const int hc = h * 64;

  // Q B-frags: wave's own 16 q rows only. aq[h2]: B[q=16w+l16][hd=quad*8+j+32*h2]
  const bf16x8 aq0 = *(const bf16x8*)&Qf[(size_t)(r0 + 16 * wave + l16) * CCH + hc + quad * 8];
  const bf16x8 aq1 = *(const bf16x8*)&Qf[(size_t)(r0 + 16 * wave + l16) * CCH + hc + quad * 8 + 32];

  // key order: for p != ii ascending: gathered[p][0..287]; then own tokens 0..575
  for (int j = tid; j < TKEYS; j += 256) {
    int row;
    if (j < 4 * NSEL) {
      const int jp = j / NSEL;
      const int jj = j - jp * NSEL;
      const int p  = jp + (jp >= ii ? 1 : 0);
      row = (s * PIMG + p) * TTOK + indices[p * NSEL + jj];
    } else {
      row = si * TTOK + (j - 4 * NSEL);
    }
    kvrow[j] = (unsigned short)row;
  }
  __syncthreads();  // kvrow ready

  // sig'(16kg + l16) = koff(kg) + chi(l16); koff = {0,4,32,36}, disjoint bits.
  const int chi  = ((l16 & 12) << 1) | (l16 & 3);
  const int jrow = tid >> 3;        // 0..31: stages keys 2*jrow, 2*jrow+1
  const int cdim = (tid & 7) * 8;   // dim chunk for V staging

  auto load_v = [&](int kt, bf16x8& c, bf16x8& d) {
    const unsigned int pr = *(const unsigned int*)&kvrow[kt * 64 + 2 * jrow];
    const int ra = pr & 0xffff;
    const int rb = pr >> 16;
    c = *(const bf16x8*)&Vf[(size_t)ra * CCH + hc + cdim];
    d = *(const bf16x8*)&Vf[(size_t)rb * CCH + hc + cdim];
  };

  bf16x8 cv0, cv1, nv0, nv1;
  load_v(0, cv0, cv1);

  float lsum = 0.f;
  f32x4 oacc[4];
#pragma unroll
  for (int dg = 0; dg < 4; ++dg) oacc[dg] = (f32x4){0.f, 0.f, 0.f, 0.f};

  for (int kt = 0; kt < KT_TILES; ++kt) {
    // ---- commit staged V tile: key-pairs packed as dwords, swizzled ----
    // byte bank = jrow ^ 4*(c^x) pattern -> 2-way (free). WAR on buf[kt&1] is
    // closed by barrier(kt-1): all waves' PV(kt-2) reads completed before
    // their commit(kt-1) issued (in-order lgkmcnt), barrier orders the rest.
    {
      unsigned int* V32 = (unsigned int*)&Vts[kt & 1][0];
      const unsigned short* s0 = (const unsigned short*)&cv0;
      const unsigned short* s1 = (const unsigned short*)&cv1;
#pragma unroll
      for (int x = 0; x < 8; ++x) {
        const int col2 = jrow ^ ((cdim ^ (x << 3)) >> 1);  // col/2
        V32[(cdim + x) * 32 + col2] = (unsigned int)s0[x] | ((unsigned int)s1[x] << 16);
      }
    }

    if (kt + 1 < KT_TILES) load_v(kt + 1, nv0, nv1);  // in flight during QK^T

    // ---- S^T = K Q^T: all 64 keys (sig'-permuted gather) x wave's 16 q ----
    f32x4 sacc[4];
#pragma unroll
    for (int kg = 0; kg < 4; ++kg) {
      const int koff = (kg >> 1) * 32 + (kg & 1) * 4;
      const int krow = kvrow[kt * 64 + koff + chi];
      const bf16x8 kf0 = *(const bf16x8*)&Kf[(size_t)krow * CCH + hc + quad * 8];
      const bf16x8 kf1 = *(const bf16x8*)&Kf[(size_t)krow * CCH + hc + quad * 8 + 32];
      f32x4 z = (f32x4){0.f, 0.f, 0.f, 0.f};
      z = MFMA_BF16(kf0, aq0, z);
      z = MFMA_BF16(kf1, aq1, z);
      sacc[kg] = z;
    }

    // ---- softmax (m=0), P packed IN-LANE into the PV A-frags ----
    // lane (quad,l16) sacc[kg][r] = P[q=16w+l16][key=32*(kg>>1)+8*quad+4*(kg&1)+r]
    // -> pa0 elem (kg&1)*4+r for kg<2 (keys 8q+j), pa1 for kg>=2 (keys 32+8q+j).
    bf16x8 pa0, pa1;
    float ls = 0.f;
#pragma unroll
    for (int kg = 0; kg < 4; ++kg) {
#pragma unroll
      for (int r = 0; r < 4; ++r) {
        const float pv = __expf(sacc[kg][r]);
        ls += pv;
        const int e = (kg & 1) * 4 + r;
        if (kg < 2) pa0[e] = (bf16_t)pv;
        else        pa1[e] = (bf16_t)pv;
      }
    }
    lsum += ls;

    __syncthreads();  // Vts[kt&1] visible

    // ---- O[16w..+15][all 64 d] += P V ; B-frags from swizzled V^T ----
    const bf16_t* __restrict__ Vb = &Vts[kt & 1][0];
#pragma unroll
    for (int dg = 0; dg < 4; ++dg) {
      const int d  = 16 * dg + l16;
      const int sw = (d & 56) ^ ((d & 7) << 3);
      const bf16x8 vf0 = *(const bf16x8*)&Vb[d * 64 + ((8 * quad) ^ sw)];
      const bf16x8 vf1 = *(const bf16x8*)&Vb[d * 64 + ((32 + 8 * quad) ^ sw)];
      oacc[dg] = MFMA_BF16(pa0, vf0, oacc[dg]);
      oacc[dg] = MFMA_BF16(pa1, vf1, oacc[dg]);
    }

    cv0 = nv0; cv1 = nv1;
  }

  __syncthreads();  // drain before aliasing Vts as scratch

  // ---- merge l partials (4 quads hold disjoint key-subsets of each q) ----
  float* lred = (float*)&Vts[0][0];  // 64 q x 4 quad floats = 1 KB
  lred[(16 * wave + l16) * 4 + quad] = lsum;
  __syncthreads();
#pragma unroll
  for (int r = 0; r < 4; ++r) {
    const int qloc = 16 * wave + 4 * quad + r;
    const float tt = lred[qloc * 4 + 0] + lred[qloc * 4 + 1] +
                     lred[qloc * 4 + 2] + lred[qloc * 4 + 3];
    const float inv = 1.f / tt;
#pragma unroll
    for (int dg = 0; dg < 4; ++dg)
      Ofull[(size_t)(r0 + qloc) * CCH + hc + 16 * dg + l16] =
          (bf16_t)(oacc[dg][r] * inv);
  }
}

}  // namespace

extern "C" void kernel_launch(void* const* d_in, const int* in_sizes, int n_in,
                              void* d_out, int out_size, void* d_ws, size_t ws_size,
                              hipStream_t stream) {
  const float* hs = (const float*)d_in[0];
  const float* Wq = (const float*)d_in[1];
  const float* Wk = (const float*)d_in[2];
  const float* Wv = (const float*)d_in[3];
  const float* Wo = (const float*)d_in[4];
  const float* bo = (const float*)d_in[5];
  const int* indices = (const int*)d_in[6];
  float* out = (float*)d_out;

  // ws layout (bf16): Qf, Kf, Vf, Xb(->Of after qkv gemm), Wqb, Wkb, Wvb, Wob = 72.1 MB
  bf16_t* Qf  = (bf16_t*)d_ws;
  bf16_t* Kf  = Qf + NXE;
  bf16_t* Vf  = Kf + NXE;
  bf16_t* Xb  = Vf + NXE;     // dead after qkv gemm
  bf16_t* Of  = Xb;           // attn output reuses the slot
  bf16_t* Wqb = Xb + NXE;
  bf16_t* Wkb = Wqb + NWE;
  bf16_t* Wvb = Wkb + NWE;
  bf16_t* Wob = Wvb + NWE;

  dim3 g0((NXE + 2047) / 2048, 5);
  cvt_kernel<<<g0, dim3(256), 0, stream>>>(hs, Wq, Wk, Wv, Wo, Xb, Wqb, Wkb, Wvb, Wob);

  dim3 g1(ROWS / 128, CCH / 128, 3);
  qkv_gemm_kernel<<<g1, dim3(256), 0, stream>>>(Xb, Wqb, Wkb, Wvb, Qf, Kf, Vf);

  attn_kernel<<<dim3(1800), dim3(256), 0, stream>>>(Qf, Kf, Vf, indices, Of);

  dim3 g3(ROWS / 128, CCH / 128, 1);
  out_gemm_kernel<<<g3, dim3(256), 0, stream>>>(Of, Wob, bo, out);
}

// Round 6
// 303.015 us; speedup vs baseline: 1.9738x; 1.3846x over previous
//
#include <hip/hip_runtime.h>

typedef __bf16 bf16_t;
typedef __attribute__((ext_vector_type(4))) __bf16 bf16x4;
typedef __attribute__((ext_vector_type(8))) __bf16 bf16x8;
typedef __attribute__((ext_vector_type(4))) float f32x4;

#define MFMA_BF16(a, b, c) __builtin_amdgcn_mfma_f32_16x16x32_bf16((a), (b), (c), 0, 0, 0)

namespace {

constexpr int PIMG  = 5;
constexpr int TTOK  = 576;
constexpr int CCH   = 1280;
constexpr int NSEL  = 288;
constexpr int NH    = 20;
constexpr int ROWS  = 2 * PIMG * TTOK;     // 5760
constexpr int TKEYS = 4 * NSEL + TTOK;     // 1728
constexpr int KT_TILES = TKEYS / 64;       // 27
constexpr size_t NXE = (size_t)ROWS * CCH;   // 7372800
constexpr size_t NWE = (size_t)CCH * CCH;    // 1638400

__device__ __forceinline__ bf16x8 cvt8(const float* p) {
  const float4 f0 = *(const float4*)p;
  const float4 f1 = *(const float4*)(p + 4);
  bf16x8 r;
  r[0] = (bf16_t)f0.x; r[1] = (bf16_t)f0.y; r[2] = (bf16_t)f0.z; r[3] = (bf16_t)f0.w;
  r[4] = (bf16_t)f1.x; r[5] = (bf16_t)f1.y; r[6] = (bf16_t)f1.z; r[7] = (bf16_t)f1.w;
  return r;
}

// ---- one-shot f32 -> bf16 conversion of X and the 4 weight matrices ----
__global__ __launch_bounds__(256) void cvt_kernel(
    const float* __restrict__ X, const float* __restrict__ W0, const float* __restrict__ W1,
    const float* __restrict__ W2, const float* __restrict__ W3,
    bf16_t* __restrict__ Xb, bf16_t* __restrict__ Wb0, bf16_t* __restrict__ Wb1,
    bf16_t* __restrict__ Wb2, bf16_t* __restrict__ Wb3) {
  const int y = blockIdx.y;
  const float* src = y == 0 ? X : (y == 1 ? W0 : (y == 2 ? W1 : (y == 3 ? W2 : W3)));
  bf16_t* dst = y == 0 ? Xb : (y == 1 ? Wb0 : (y == 2 ? Wb1 : (y == 3 ? Wb2 : Wb3)));
  const size_t n = y == 0 ? NXE : NWE;
  const size_t idx = ((size_t)blockIdx.x * 256 + threadIdx.x) * 8;
  if (idx < n) *(bf16x8*)&dst[idx] = cvt8(&src[idx]);
}

// NT GEMM: C[m][n] = sum_k A[m][k]*B[n][k] (+bias) (*scale), bf16 in, fp32 acc.
// 128x128 tile, BK=64, register-prefetch pipeline (measured best of 3 variants).
template <bool BIAS, typename CT>
__device__ __forceinline__ void gemm_nt_body(const bf16_t* __restrict__ A,
                                             const bf16_t* __restrict__ B,
                                             const float* __restrict__ bias,
                                             CT* __restrict__ C,
                                             int bm, int bn, float scale) {
  constexpr int LDT = 72;  // 64 + 8 pad
  __shared__ bf16_t As[128 * LDT];
  __shared__ bf16_t Bs[128 * LDT];

  const int tid  = threadIdx.x;
  const int lane = tid & 63;
  const int wave = tid >> 6;
  const int quad = lane >> 4;
  const int l16  = lane & 15;
  const int wr   = (wave >> 1) * 64;
  const int wc   = (wave & 1) * 64;
  const int m0   = bm * 128;
  const int n0   = bn * 128;
  const int srow = tid >> 3;        // 0..31 (+32p)
  const int scol = (tid & 7) * 8;   // 0..56

  bf16x8 pa[4], pb[4];
  auto loadAB = [&](int k0) {
#pragma unroll
    for (int p = 0; p < 4; ++p) {
      pa[p] = *(const bf16x8*)&A[(size_t)(m0 + srow + 32 * p) * CCH + k0 + scol];
      pb[p] = *(const bf16x8*)&B[(size_t)(n0 + srow + 32 * p) * CCH + k0 + scol];
    }
  };
  loadAB(0);

  f32x4 acc[4][4];
#pragma unroll
  for (int i = 0; i < 4; ++i)
#pragma unroll
    for (int j = 0; j < 4; ++j) acc[i][j] = (f32x4){0.f, 0.f, 0.f, 0.f};

  for (int it = 0; it < CCH / 64; ++it) {
#pragma unroll
    for (int p = 0; p < 4; ++p) {
      *(bf16x8*)&As[(srow + 32 * p) * LDT + scol] = pa[p];
      *(bf16x8*)&Bs[(srow + 32 * p) * LDT + scol] = pb[p];
    }
    __syncthreads();
    if (it < CCH / 64 - 1) loadAB((it + 1) * 64);  // in flight during compute
#pragma unroll
    for (int ks = 0; ks < 2; ++ks) {
      bf16x8 af[4], bfr[4];
#pragma unroll
      for (int i = 0; i < 4; ++i)
        af[i] = *(const bf16x8*)&As[(wr + 16 * i + l16) * LDT + ks * 32 + quad * 8];
#pragma unroll
      for (int j = 0; j < 4; ++j)
        bfr[j] = *(const bf16x8*)&Bs[(wc + 16 * j + l16) * LDT + ks * 32 + quad * 8];
#pragma unroll
      for (int i = 0; i < 4; ++i)
#pragma unroll
        for (int j = 0; j < 4; ++j)
          acc[i][j] = MFMA_BF16(af[i], bfr[j], acc[i][j]);
    }
    if (it < CCH / 64 - 1) __syncthreads();
  }

  // epilogue: C/D layout col = l16, row = quad*4 + r
#pragma unroll
  for (int j = 0; j < 4; ++j) {
    const int col = n0 + wc + 16 * j + l16;
    const float bv = BIAS ? bias[col] : 0.f;
#pragma unroll
    for (int i = 0; i < 4; ++i) {
#pragma unroll
      for (int r = 0; r < 4; ++r) {
        const int row = m0 + wr + 16 * i + quad * 4 + r;
        const float val = acc[i][j][r] * scale + bv;
        if constexpr (sizeof(CT) == 2)
          C[(size_t)row * CCH + col] = (CT)val;
        else
          C[(size_t)row * CCH + col] = val;
      }
    }
  }
}

__global__ __launch_bounds__(256, 3) void qkv_gemm_kernel(
    const bf16_t* __restrict__ Xb,
    const bf16_t* __restrict__ Wqb, const bf16_t* __restrict__ Wkb, const bf16_t* __restrict__ Wvb,
    bf16_t* __restrict__ Qf, bf16_t* __restrict__ Kf, bf16_t* __restrict__ Vf) {
  const bf16_t* W = blockIdx.z == 0 ? Wqb : (blockIdx.z == 1 ? Wkb : Wvb);
  bf16_t* O = blockIdx.z == 0 ? Qf : (blockIdx.z == 1 ? Kf : Vf);
  const float scl = blockIdx.z == 0 ? 0.125f : 1.0f;  // fold 1/sqrt(64) into Q
  gemm_nt_body<false, bf16_t>(Xb, W, nullptr, O, blockIdx.x, blockIdx.y, scl);
}

__global__ __launch_bounds__(256, 3) void out_gemm_kernel(
    const bf16_t* __restrict__ Of, const bf16_t* __restrict__ Wob,
    const float* __restrict__ bo, float* __restrict__ out) {
  gemm_nt_body<true, float>(Of, Wob, bo, out, blockIdx.x, blockIdx.y, 1.0f);
}

// Flash attention over gathered K/V rows. grid = 1800, XCD-swizzled (9 qt-siblings
// of each (si,h) group share one XCD's L2). block = 128 (2 WAVES), 64 q/block.
//
// R6 synthesis of R0..R5 evidence:
//  - R0 was LDS-throughput-bound: 56 KB/block-iter (Ps 8 + pf 32 + Vw 8 + vf 8)
//    ~= 100% of the ~85 B/cy/CU LDS pipe at 2.6 resident blocks. (Explains
//    R1 barrier-null and R2 QB-regression.)
//  - R5 cut LDS to 40% but added x4-redundant un-prefetched K gather: vmem
//    instr x2.5 -> time x2. Gather must stay x1 + prefetched (R0 pattern).
//  Design: 2 waves; wave w owns keys [32w,32w+32) END-TO-END:
//  - K gather x1/prefetched, slot-permuted (8*(l16>>2)+4kg+(l16&3)) so each
//    lane's softmax output IS its PV A-frag: P never touches LDS.
//  - PV: wave reads only its own 32 V^T columns -> x1. LDS/iter = 16 KB
//    (V write 8K + vf read 8K), R5's verified conflict-free swizzle.
//  - Each wave accumulates the FULL 64x64 O-partial over its keys (64 VGPR);
//    one f32 cross-wave sum at the end through dead-Vts LDS.
//  lb(128,2): ~200 VGPR, no spill (R4: spill = 530 MB scratch catastrophe).
//  1 barrier/iter, dbuf Vts (R1-verified WAR proof).
__global__ __launch_bounds__(128, 2) void attn_kernel(
    const bf16_t* __restrict__ Qf, const bf16_t* __restrict__ Kf, const bf16_t* __restrict__ Vf,
    const int* __restrict__ indices, bf16_t* __restrict__ Ofull) {
  __shared__ unsigned short kvrow[TKEYS];        // 3456 B; dead after loop -> lred/linv
  __shared__ __align__(16) bf16_t Vts[2][64 * 64];  // 16 KB dbuf; dead after loop -> Osc

  const int tid  = threadIdx.x;
  const int lane = tid & 63;
  const int wave = tid >> 6;     // 0..1
  const int quad = lane >> 4;
  const int l16  = lane & 15;

  // XCD swizzle: b%8 = XCD (round-robin dispatch heuristic; speed-only)
  const int b   = blockIdx.x;
  const int xcd = b & 7;
  const int t   = b >> 3;            // 0..224
  const int gi  = t / 9;
  const int qt  = t - gi * 9;        // sibling index = q-tile
  const int g   = xcd + 8 * gi;      // 0..199 group id
  const int h   = g % NH;
  const int si  = g / NH;            // s*5 + i
  const int s   = si / PIMG;
  const int ii  = si % PIMG;

  const int r0 = si * TTOK + qt * 64;
  const int hc = h * 64;

  // Q B-frags, all 64 q, loop-invariant: aq[n][h2] -> B[q=16n+l16][d=quad*8+j+32*h2]
  bf16x8 aq[4][2];
#pragma unroll
  for (int n = 0; n < 4; ++n)
#pragma unroll
    for (int h2 = 0; h2 < 2; ++h2)
      aq[n][h2] = *(const bf16x8*)&Qf[(size_t)(r0 + 16 * n + l16) * CCH + hc + quad * 8 + 32 * h2];

  // key order: for p != ii ascending: gathered[p][0..287]; then own tokens 0..575
  for (int j = tid; j < TKEYS; j += 128) {
    int row;
    if (j < 4 * NSEL) {
      const int jp = j / NSEL;
      const int jj = j - jp * NSEL;
      const int p  = jp + (jp >= ii ? 1 : 0);
      row = (s * PIMG + p) * TTOK + indices[p * NSEL + jj];
    } else {
      row = si * TTOK + (j - 4 * NSEL);
    }
    kvrow[j] = (unsigned short)row;
  }
  __syncthreads();  // kvrow ready

  // K slot permutation: slot(kg) = 32w + 8*(l16>>2) + 4*kg + (l16&3).
  // With it, QK^T output element (kg,quad,r) = key 32w+8*quad+4*kg+r, which is
  // exactly PV A-frag elem j = 4*kg+r at k = 8*quad+j. P stays in registers.
  const int kidx = 32 * wave + ((l16 >> 2) << 3) + (l16 & 3);

  const int va = tid >> 3;        // 0..15: stages rows 4va..4va+3 (pairs 2va,2va+1)
  const int vc = (tid & 7) * 8;   // dim chunk

  bf16x8 kq[2][2], kn[2][2], vs[4], vn[4];
#pragma unroll
  for (int kg = 0; kg < 2; ++kg) {
    const int krow = kvrow[kidx + 4 * kg];
    kq[kg][0] = *(const bf16x8*)&Kf[(size_t)krow * CCH + hc + quad * 8];
    kq[kg][1] = *(const bf16x8*)&Kf[(size_t)krow * CCH + hc + quad * 8 + 32];
  }
#pragma unroll
  for (int e = 0; e < 4; ++e)
    vs[e] = *(const bf16x8*)&Vf[(size_t)kvrow[4 * va + e] * CCH + hc + vc];

  float l_part[4] = {0.f, 0.f, 0.f, 0.f};
  f32x4 oacc[4][4];
#pragma unroll
  for (int n = 0; n < 4; ++n)
#pragma unroll
    for (int dg = 0; dg < 4; ++dg) oacc[n][dg] = (f32x4){0.f, 0.f, 0.f, 0.f};

  for (int kt = 0; kt < KT_TILES; ++kt) {
    // ---- commit staged V tile: key-pairs packed as dwords, swizzled ----
    // storage: V[key][d] at bf16 col (key ^ ((d&56)^((d&7)<<3))); pair-word
    // col2 = p ^ 4(c^x). 2-way write aliasing (free). WAR on buf[kt&1]: all
    // waves' reads at kt-2 completed before their own barrier(kt-1) arrival
    // (in-order LDS + MFMA consumption), so writes here are safe.
    {
      unsigned int* V32 = (unsigned int*)&Vts[kt & 1][0];
      const unsigned short* q0 = (const unsigned short*)&vs[0];
      const unsigned short* q1 = (const unsigned short*)&vs[1];
      const unsigned short* q2 = (const unsigned short*)&vs[2];
      const unsigned short* q3 = (const unsigned short*)&vs[3];
#pragma unroll
      for (int x = 0; x < 8; ++x) {
        const int sx = (vc >> 1) ^ (x << 2);   // 4*(c^x)
        V32[(vc + x) * 32 + ((2 * va) ^ sx)]     = (unsigned int)q0[x] | ((unsigned int)q1[x] << 16);
        V32[(vc + x) * 32 + ((2 * va + 1) ^ sx)] = (unsigned int)q2[x] | ((unsigned int)q3[x] << 16);
      }
    }

    // ---- prefetch tile kt+1 (x1 across block, one iteration of slack) ----
    if (kt + 1 < KT_TILES) {
      const int kb = (kt + 1) * 64;
#pragma unroll
      for (int kg = 0; kg < 2; ++kg) {
        const int krow = kvrow[kb + kidx + 4 * kg];
        kn[kg][0] = *(const bf16x8*)&Kf[(size_t)krow * CCH + hc + quad * 8];
        kn[kg][1] = *(const bf16x8*)&Kf[(size_t)krow * CCH + hc + quad * 8 + 32];
      }
#pragma unroll
      for (int e = 0; e < 4; ++e)
        vn[e] = *(const bf16x8*)&Vf[(size_t)kvrow[kb + 4 * va + e] * CCH + hc + vc];
    }

    // ---- S^T = K Q^T (wave's 32 keys x all 64 q) + softmax into A-frags ----
    bf16x8 pa[4];
#pragma unroll
    for (int kg = 0; kg < 2; ++kg) {
#pragma unroll
      for (int n = 0; n < 4; ++n) {
        f32x4 z = (f32x4){0.f, 0.f, 0.f, 0.f};
        z = MFMA_BF16(kq[kg][0], aq[n][0], z);
        z = MFMA_BF16(kq[kg][1], aq[n][1], z);
#pragma unroll
        for (int r = 0; r < 4; ++r) {
          const float pv = __expf(z[r]);
          l_part[n] += pv;
          pa[n][4 * kg + r] = (bf16_t)pv;
        }
      }
    }

    __syncthreads();  // Vts[kt&1] visible (the ONLY barrier per iteration)

    // ---- O_partial[all 64 q][all 64 d] += P(wave keys) V(wave keys) ----
    const bf16_t* __restrict__ Vb = &Vts[kt & 1][0];
#pragma unroll
    for (int dg = 0; dg < 4; ++dg) {
      const int d  = 16 * dg + l16;
      const int sw = (d & 56) ^ ((d & 7) << 3);
      const bf16x8 vf = *(const bf16x8*)&Vb[d * 64 + ((32 * wave + 8 * quad) ^ sw)];
#pragma unroll
      for (int n = 0; n < 4; ++n)
        oacc[n][dg] = MFMA_BF16(pa[n], vf, oacc[n][dg]);
    }

    // rotate prefetched registers (R0-proven pattern)
#pragma unroll
    for (int kg = 0; kg < 2; ++kg) {
      kq[kg][0] = kn[kg][0];
      kq[kg][1] = kn[kg][1];
    }
#pragma unroll
    for (int e = 0; e < 4; ++e) vs[e] = vn[e];
  }

  __syncthreads();  // drain before aliasing kvrow/Vts as scratch

  // ---- merge l partials: 8 per q (2 waves x 4 quads) ----
  float* lred = (float*)kvrow;        // 512 f32 = 2048 B <= 3456
  float* linv = lred + 512;           // 64 f32
#pragma unroll
  for (int n = 0; n < 4; ++n)
    lred[(16 * n + l16) * 8 + 4 * wave + quad] = l_part[n];
  __syncthreads();
  if (tid < 64) {
    float tt = 0.f;
#pragma unroll
    for (int i = 0; i < 8; ++i) tt += lred[tid * 8 + i];
    linv[tid] = 1.f / tt;
  }
  __syncthreads();

  // ---- cross-wave O sum (f32 through dead Vts) + scaled write ----
  float* Osc = (float*)&Vts[0][0];    // 64*64 f32 = 16384 B (exact fit)
  if (wave == 0) {
#pragma unroll
    for (int n = 0; n < 4; ++n)
#pragma unroll
      for (int r = 0; r < 4; ++r) {
        const int q = 16 * n + 4 * quad + r;
#pragma unroll
        for (int dg = 0; dg < 4; ++dg)
          Osc[q * 64 + 16 * dg + l16] = oacc[n][dg][r];
      }
  }
  __syncthreads();
  if (wave == 1) {
#pragma unroll
    for (int n = 0; n < 4; ++n)
#pragma unroll
      for (int r = 0; r < 4; ++r) {
        const int q   = 16 * n + 4 * quad + r;
        const float inv = linv[q];
#pragma unroll
        for (int dg = 0; dg < 4; ++dg) {
          const float val = (Osc[q * 64 + 16 * dg + l16] + oacc[n][dg][r]) * inv;
          Ofull[(size_t)(r0 + q) * CCH + hc + 16 * dg + l16] = (bf16_t)val;
        }
      }
  }
}

}  // namespace

extern "C" void kernel_launch(void* const* d_in, const int* in_sizes, int n_in,
                              void* d_out, int out_size, void* d_ws, size_t ws_size,
                              hipStream_t stream) {
  const float* hs = (const float*)d_in[0];
  const float* Wq = (const float*)d_in[1];
  const float* Wk = (const float*)d_in[2];
  const float* Wv = (const float*)d_in[3];
  const float* Wo = (const float*)d_in[4];
  const float* bo = (const float*)d_in[5];
  const int* indices = (const int*)d_in[6];
  float* out = (float*)d_out;

  // ws layout (bf16): Qf, Kf, Vf, Xb(->Of after qkv gemm), Wqb, Wkb, Wvb, Wob = 72.1 MB
  bf16_t* Qf  = (bf16_t*)d_ws;
  bf16_t* Kf  = Qf + NXE;
  bf16_t* Vf  = Kf + NXE;
  bf16_t* Xb  = Vf + NXE;     // dead after qkv gemm
  bf16_t* Of  = Xb;           // attn output reuses the slot
  bf16_t* Wqb = Xb + NXE;
  bf16_t* Wkb = Wqb + NWE;
  bf16_t* Wvb = Wkb + NWE;
  bf16_t* Wob = Wvb + NWE;

  dim3 g0((NXE + 2047) / 2048, 5);
  cvt_kernel<<<g0, dim3(256), 0, stream>>>(hs, Wq, Wk, Wv, Wo, Xb, Wqb, Wkb, Wvb, Wob);

  dim3 g1(ROWS / 128, CCH / 128, 3);
  qkv_gemm_kernel<<<g1, dim3(256), 0, stream>>>(Xb, Wqb, Wkb, Wvb, Qf, Kf, Vf);

  attn_kernel<<<dim3(1800), dim3(128), 0, stream>>>(Qf, Kf, Vf, indices, Of);

  dim3 g3(ROWS / 128, CCH / 128, 1);
  out_gemm_kernel<<<g3, dim3(256), 0, stream>>>(Of, Wob, bo, out);
}